// Round 6
// baseline (5207.783 us; speedup 1.0000x reference)
//
#include <hip/hip_runtime.h>
#include <math.h>

#define H 1024
#define BB 64
#define TT 256
#define G3 3072

typedef __attribute__((ext_vector_type(8))) short bf16x8;
typedef __attribute__((ext_vector_type(4))) float f32x4;

__device__ __forceinline__ unsigned short f2bf(float f) {
    union { float f; unsigned int i; } v; v.f = f;
    unsigned int x = v.i;
    unsigned int r = (x + 0x7fffu + ((x >> 16) & 1u)) >> 16;   // RNE
    return (unsigned short)r;
}
__device__ __forceinline__ float bf2f(unsigned short u) {
    union { unsigned int i; float f; } v; v.i = ((unsigned int)u) << 16; return v.f;
}

// f32 -> bf16 bulk convert (for W_ih / W_hh), 4 elems/thread
__global__ void cvt_f32_bf16(const float* __restrict__ src,
                             unsigned short* __restrict__ dst) {
    int i = (blockIdx.x * 256 + threadIdx.x) * 4;
    float4 v = *(const float4*)(src + i);
    ushort4 o;
    o.x = f2bf(v.x); o.y = f2bf(v.y); o.z = f2bf(v.z); o.w = f2bf(v.w);
    *(ushort4*)(dst + i) = o;
}

// h init: hf = h0 (f32), hb = bf16(h0)
__global__ void init_h(const float* __restrict__ h0,
                       float* __restrict__ hf, unsigned short* __restrict__ hb) {
    int i = blockIdx.x * 256 + threadIdx.x;
    float v = h0[i];
    hf[i] = v;
    hb[i] = f2bf(v);
}

// load 8 consecutive f32, relu, convert to bf16x8
__device__ __forceinline__ bf16x8 load8_relu_bf(const float* p) {
    float4 u = *(const float4*)p;
    float4 v = *(const float4*)(p + 4);
    bf16x8 r;
    r[0] = (short)f2bf(fmaxf(u.x, 0.f));
    r[1] = (short)f2bf(fmaxf(u.y, 0.f));
    r[2] = (short)f2bf(fmaxf(u.z, 0.f));
    r[3] = (short)f2bf(fmaxf(u.w, 0.f));
    r[4] = (short)f2bf(fmaxf(v.x, 0.f));
    r[5] = (short)f2bf(fmaxf(v.y, 0.f));
    r[6] = (short)f2bf(fmaxf(v.z, 0.f));
    r[7] = (short)f2bf(fmaxf(v.w, 0.f));
    return r;
}

// ---- xp_chunk = relu(emb[tokens]) @ W_ih^T + b_ih -> bf16 [Tl*64, 3072] ----
// A: fused gather+relu+cvt from f32 emb. B: pre-converted bf16 W_ih [N,K].
// 128x128 tile, 4 waves 2x2, each wave 64x64 via 4x4 MFMA 16x16x32 bf16.
__global__ __launch_bounds__(256) void gemm_xp(
    const float* __restrict__ emb,             // [32000, 1024] f32
    const int* __restrict__ tokens,            // [16384] flat (T*B)
    const unsigned short* __restrict__ Wb,     // [3072, 1024] bf16
    const float* __restrict__ b_ih,            // [3072] f32
    unsigned short* __restrict__ xp,           // chunk-local bf16
    int row0)
{
    const int tileN = blockIdx.x * 128;
    const int tileM = blockIdx.y * 128;        // chunk-local
    const int wave  = threadIdx.x >> 6;
    const int lane  = threadIdx.x & 63;
    const int row   = lane & 15;
    const int quad  = lane >> 4;
    const int mb = tileM + (wave >> 1) * 64;
    const int nb = tileN + (wave & 1) * 64;

    const float* arow[4];
#pragma unroll
    for (int i = 0; i < 4; i++) {
        int tok = tokens[row0 + mb + row + i * 16];
        arow[i] = emb + (size_t)tok * H + quad * 8;
    }
    const unsigned short* bptr = Wb + (size_t)(nb + row) * H + quad * 8;

    f32x4 acc[4][4] = {};
    for (int k = 0; k < H; k += 32) {
        bf16x8 a[4], b[4];
#pragma unroll
        for (int i = 0; i < 4; i++) a[i] = load8_relu_bf(arow[i] + k);
#pragma unroll
        for (int j = 0; j < 4; j++) b[j] = *(const bf16x8*)(bptr + (size_t)j * 16 * H + k);
#pragma unroll
        for (int i = 0; i < 4; i++)
#pragma unroll
            for (int j = 0; j < 4; j++)
                acc[i][j] = __builtin_amdgcn_mfma_f32_16x16x32_bf16(a[i], b[j], acc[i][j], 0, 0, 0);
    }

#pragma unroll
    for (int i = 0; i < 4; i++) {
        int m = mb + i * 16 + quad * 4;
#pragma unroll
        for (int j = 0; j < 4; j++) {
            int n = nb + j * 16 + row;
            float bias = b_ih[n];
#pragma unroll
            for (int rg = 0; rg < 4; rg++) {
                xp[(size_t)(m + rg) * G3 + n] = f2bf(acc[i][j][rg] + bias);
            }
        }
    }
}

// ---- one GRU step: 64 WGs; WG jb owns h-cols [jb*16, jb*16+16) ----
__global__ __launch_bounds__(256) void gru_step(
    const unsigned short* __restrict__ h_in_bf,   // [64,1024] bf16
    const float* __restrict__ h_in_f32,           // [64,1024] f32
    const unsigned short* __restrict__ Whb,       // [3072,1024] bf16
    const float* __restrict__ b_hh,               // [3072] f32
    const unsigned short* __restrict__ xp_t,      // [64,3072] bf16
    float* __restrict__ h_out_f32,
    unsigned short* __restrict__ h_out_bf,
    float* __restrict__ out,                      // [B,T,H] f32
    int t)
{
    const int j0   = blockIdx.x * 16;
    const int wave = threadIdx.x >> 6;
    const int lane = threadIdx.x & 63;
    const int row  = lane & 15;
    const int quad = lane >> 4;
    const int m0   = wave * 16;

    f32x4 acc0 = {}, acc1 = {}, acc2 = {};
    const unsigned short* aptr = h_in_bf + (m0 + row) * H + quad * 8;
    const unsigned short* b0 = Whb + (size_t)(0 * H + j0 + row) * H + quad * 8;
    const unsigned short* b1 = Whb + (size_t)(1 * H + j0 + row) * H + quad * 8;
    const unsigned short* b2 = Whb + (size_t)(2 * H + j0 + row) * H + quad * 8;

    for (int k = 0; k < H; k += 32) {
        bf16x8 a  = *(const bf16x8*)(aptr + k);
        bf16x8 f0 = *(const bf16x8*)(b0 + k);
        bf16x8 f1 = *(const bf16x8*)(b1 + k);
        bf16x8 f2 = *(const bf16x8*)(b2 + k);
        acc0 = __builtin_amdgcn_mfma_f32_16x16x32_bf16(a, f0, acc0, 0, 0, 0);
        acc1 = __builtin_amdgcn_mfma_f32_16x16x32_bf16(a, f1, acc1, 0, 0, 0);
        acc2 = __builtin_amdgcn_mfma_f32_16x16x32_bf16(a, f2, acc2, 0, 0, 0);
    }

    const int cj = j0 + row;
    const float bhr = b_hh[cj];
    const float bhz = b_hh[H + cj];
    const float bhn = b_hh[2 * H + cj];

#pragma unroll
    for (int i = 0; i < 4; i++) {
        int b = m0 + quad * 4 + i;
        const unsigned short* xpb = xp_t + (size_t)b * G3;
        float xr = bf2f(xpb[cj]);
        float xz = bf2f(xpb[H + cj]);
        float xn = bf2f(xpb[2 * H + cj]);
        float hr = acc0[i] + bhr;
        float hz = acc1[i] + bhz;
        float hn = acc2[i] + bhn;
        float r = 1.f / (1.f + __expf(-(xr + hr)));
        float z = 1.f / (1.f + __expf(-(xz + hz)));
        float targ = xn + r * hn;
        targ = fminf(fmaxf(targ, -30.f), 30.f);
        float n = tanhf(targ);
        float hprev = h_in_f32[b * H + cj];
        float hnew = (1.f - z) * n + z * hprev;
        hnew = fminf(fmaxf(hnew, -4.f), 4.f);   // invisible when correct (|h|<=1)
        h_out_f32[b * H + cj] = hnew;
        h_out_bf[b * H + cj] = f2bf(hnew);
        out[((size_t)b * TT + t) * H + cj] = hnew;
    }
}

extern "C" void kernel_launch(void* const* d_in, const int* in_sizes, int n_in,
                              void* d_out, int out_size, void* d_ws, size_t ws_size,
                              hipStream_t stream) {
    const int*   tokens = (const int*)d_in[0];
    const float* h0     = (const float*)d_in[1];
    const float* emb    = (const float*)d_in[2];
    const float* W_ih   = (const float*)d_in[3];
    const float* W_hh   = (const float*)d_in[4];
    const float* b_ih   = (const float*)d_in[5];
    const float* b_hh   = (const float*)d_in[6];
    float*       out    = (float*)d_out;

    // ws: [0,1MiB) h state | [1MiB,+6MiB) W_ih bf16 | +6MiB W_hh bf16 | xp chunk.
    // xp chunk length Tc adapts to ws_size (never reads past the workspace).
    char* ws = (char*)d_ws;
    float* hf0 = (float*)ws;                                // 256 KiB
    float* hf1 = hf0 + BB * H;                              // 256 KiB
    unsigned short* hb0 = (unsigned short*)(ws + 524288);   // 128 KiB
    unsigned short* hb1 = hb0 + BB * H;                     // 128 KiB
    unsigned short* Wib = (unsigned short*)(ws + 1048576);          // 6,291,456 B
    unsigned short* Whb = (unsigned short*)(ws + 1048576 + 6291456);// 6,291,456 B
    unsigned short* xp  = (unsigned short*)(ws + 13631488);

    const size_t slab = (size_t)BB * G3 * 2;                // 393,216 B per t
    long avail = (long)ws_size - 13631488L;
    if (avail < 0) avail = 0;
    long tc = (avail / (long)slab) & ~1L;                   // even
    if (tc < 2) tc = 2;
    if (tc > TT) tc = TT;
    const int Tc = (int)tc;

    hipLaunchKernelGGL(cvt_f32_bf16, dim3(G3 * H / 1024), dim3(256), 0, stream, W_ih, Wib);
    hipLaunchKernelGGL(cvt_f32_bf16, dim3(G3 * H / 1024), dim3(256), 0, stream, W_hh, Whb);
    hipLaunchKernelGGL(init_h, dim3((BB * H) / 256), dim3(256), 0, stream, h0, hf0, hb0);

    for (int c0 = 0; c0 < TT; c0 += Tc) {
        const int Tl = (TT - c0 < Tc) ? (TT - c0) : Tc;     // even
        hipLaunchKernelGGL(gemm_xp, dim3(G3 / 128, Tl * BB / 128), dim3(256), 0, stream,
                           emb, tokens, Wib, b_ih, xp, c0 * BB);
        for (int t = c0; t < c0 + Tl; t++) {
            const unsigned short* hin_b = (t & 1) ? hb1 : hb0;
            const float*          hin_f = (t & 1) ? hf1 : hf0;
            unsigned short* hout_b = (t & 1) ? hb0 : hb1;
            float*          hout_f = (t & 1) ? hf0 : hf1;
            const unsigned short* xp_t = xp + (size_t)(t - c0) * BB * G3;
            hipLaunchKernelGGL(gru_step, dim3(H / 16), dim3(256), 0, stream,
                               hin_b, hin_f, Whb, b_hh, xp_t, hout_f, hout_b, out, t);
        }
    }
}

// Round 7
// 4999.418 us; speedup vs baseline: 1.0417x; 1.0417x over previous
//
#include <hip/hip_runtime.h>
#include <math.h>

#define H 1024
#define BB 64
#define TT 256
#define G3 3072
#define SCAN_BLOCKS 64

typedef __attribute__((ext_vector_type(8))) short bf16x8;
typedef __attribute__((ext_vector_type(4))) float f32x4;

__device__ __forceinline__ unsigned short f2bf(float f) {
    union { float f; unsigned int i; } v; v.f = f;
    unsigned int x = v.i;
    unsigned int r = (x + 0x7fffu + ((x >> 16) & 1u)) >> 16;   // RNE
    return (unsigned short)r;
}
__device__ __forceinline__ float bf2f(unsigned short u) {
    union { unsigned int i; float f; } v; v.i = ((unsigned int)u) << 16; return v.f;
}

// f32 -> bf16 bulk convert (for W_ih / W_hh), 4 elems/thread
__global__ void cvt_f32_bf16(const float* __restrict__ src,
                             unsigned short* __restrict__ dst) {
    int i = (blockIdx.x * 256 + threadIdx.x) * 4;
    float4 v = *(const float4*)(src + i);
    ushort4 o;
    o.x = f2bf(v.x); o.y = f2bf(v.y); o.z = f2bf(v.z); o.w = f2bf(v.w);
    *(ushort4*)(dst + i) = o;
}

// init: hf = h0 (f32), hb = bf16(h0), zero the grid-barrier counter
__global__ void init_all(const float* __restrict__ h0,
                         float* __restrict__ hf, unsigned short* __restrict__ hb,
                         unsigned int* __restrict__ cnt) {
    int i = blockIdx.x * 256 + threadIdx.x;
    if (i == 0) *cnt = 0u;             // kernel boundary orders this vs scan
    float v = h0[i];
    hf[i] = v;
    hb[i] = f2bf(v);
}

// load 8 consecutive f32, relu, convert to bf16x8
__device__ __forceinline__ bf16x8 load8_relu_bf(const float* p) {
    float4 u = *(const float4*)p;
    float4 v = *(const float4*)(p + 4);
    bf16x8 r;
    r[0] = (short)f2bf(fmaxf(u.x, 0.f));
    r[1] = (short)f2bf(fmaxf(u.y, 0.f));
    r[2] = (short)f2bf(fmaxf(u.z, 0.f));
    r[3] = (short)f2bf(fmaxf(u.w, 0.f));
    r[4] = (short)f2bf(fmaxf(v.x, 0.f));
    r[5] = (short)f2bf(fmaxf(v.y, 0.f));
    r[6] = (short)f2bf(fmaxf(v.z, 0.f));
    r[7] = (short)f2bf(fmaxf(v.w, 0.f));
    return r;
}

// ---- xp_chunk = relu(emb[tokens]) @ W_ih^T + b_ih -> bf16 [Tl*64, 3072] ----
// (unchanged from the passing round)
__global__ __launch_bounds__(256) void gemm_xp(
    const float* __restrict__ emb,
    const int* __restrict__ tokens,
    const unsigned short* __restrict__ Wb,
    const float* __restrict__ b_ih,
    unsigned short* __restrict__ xp,
    int row0)
{
    const int tileN = blockIdx.x * 128;
    const int tileM = blockIdx.y * 128;
    const int wave  = threadIdx.x >> 6;
    const int lane  = threadIdx.x & 63;
    const int row   = lane & 15;
    const int quad  = lane >> 4;
    const int mb = tileM + (wave >> 1) * 64;
    const int nb = tileN + (wave & 1) * 64;

    const float* arow[4];
#pragma unroll
    for (int i = 0; i < 4; i++) {
        int tok = tokens[row0 + mb + row + i * 16];
        arow[i] = emb + (size_t)tok * H + quad * 8;
    }
    const unsigned short* bptr = Wb + (size_t)(nb + row) * H + quad * 8;

    f32x4 acc[4][4] = {};
    for (int k = 0; k < H; k += 32) {
        bf16x8 a[4], b[4];
#pragma unroll
        for (int i = 0; i < 4; i++) a[i] = load8_relu_bf(arow[i] + k);
#pragma unroll
        for (int j = 0; j < 4; j++) b[j] = *(const bf16x8*)(bptr + (size_t)j * 16 * H + k);
#pragma unroll
        for (int i = 0; i < 4; i++)
#pragma unroll
            for (int j = 0; j < 4; j++)
                acc[i][j] = __builtin_amdgcn_mfma_f32_16x16x32_bf16(a[i], b[j], acc[i][j], 0, 0, 0);
    }

#pragma unroll
    for (int i = 0; i < 4; i++) {
        int m = mb + i * 16 + quad * 4;
#pragma unroll
        for (int j = 0; j < 4; j++) {
            int n = nb + j * 16 + row;
            float bias = b_ih[n];
#pragma unroll
            for (int rg = 0; rg < 4; rg++) {
                xp[(size_t)(m + rg) * G3 + n] = f2bf(acc[i][j][rg] + bias);
            }
        }
    }
}

// ---- persistent GRU scan: one launch per xp chunk, grid barrier per step ----
// 64 blocks (<= CU count -> all co-resident). Block jb owns h-cols
// [jb*16, jb*16+16). Step body identical to the proven gru_step; hprev f32
// lives in registers (only its producing thread ever reads it).
__global__ __launch_bounds__(256) void gru_scan(
    unsigned short* __restrict__ hb0,          // bf16 h ping [64*1024]
    unsigned short* __restrict__ hb1,          // bf16 h pong
    float* __restrict__ hf,                    // f32 h (chunk handoff)
    const unsigned short* __restrict__ Whb,    // [3072,1024] bf16
    const float* __restrict__ b_hh,            // [3072] f32
    const unsigned short* __restrict__ xp,     // chunk base, [Tl*64, 3072] bf16
    float* __restrict__ out,                   // [B,T,H] f32
    unsigned int* __restrict__ cnt,            // grid-barrier counter
    int t0, int Tl)
{
    const int j0   = blockIdx.x * 16;
    const int wave = threadIdx.x >> 6;
    const int lane = threadIdx.x & 63;
    const int row  = lane & 15;
    const int quad = lane >> 4;
    const int m0   = wave * 16;
    const int cj   = j0 + row;

    const float bhr = b_hh[cj];
    const float bhz = b_hh[H + cj];
    const float bhn = b_hh[2 * H + cj];

    const unsigned short* w0 = Whb + (size_t)(0 * H + j0 + row) * H + quad * 8;
    const unsigned short* w1 = Whb + (size_t)(1 * H + j0 + row) * H + quad * 8;
    const unsigned short* w2 = Whb + (size_t)(2 * H + j0 + row) * H + quad * 8;

    float hprev[4];
#pragma unroll
    for (int i = 0; i < 4; i++) hprev[i] = hf[(m0 + quad * 4 + i) * H + cj];

    for (int s = 0; s < Tl; s++) {
        const int t = t0 + s;
        const unsigned short* hin  = (t & 1) ? hb1 : hb0;
        unsigned short*       hout = (t & 1) ? hb0 : hb1;

        f32x4 acc0 = {}, acc1 = {}, acc2 = {};
        const unsigned short* aptr = hin + (m0 + row) * H + quad * 8;
        for (int k = 0; k < H; k += 32) {
            bf16x8 a  = *(const bf16x8*)(aptr + k);
            bf16x8 f0 = *(const bf16x8*)(w0 + k);
            bf16x8 f1 = *(const bf16x8*)(w1 + k);
            bf16x8 f2 = *(const bf16x8*)(w2 + k);
            acc0 = __builtin_amdgcn_mfma_f32_16x16x32_bf16(a, f0, acc0, 0, 0, 0);
            acc1 = __builtin_amdgcn_mfma_f32_16x16x32_bf16(a, f1, acc1, 0, 0, 0);
            acc2 = __builtin_amdgcn_mfma_f32_16x16x32_bf16(a, f2, acc2, 0, 0, 0);
        }

#pragma unroll
        for (int i = 0; i < 4; i++) {
            int b = m0 + quad * 4 + i;
            const unsigned short* xpb = xp + ((size_t)s * BB + b) * G3;
            float xr = bf2f(xpb[cj]);
            float xz = bf2f(xpb[H + cj]);
            float xn = bf2f(xpb[2 * H + cj]);
            float hr = acc0[i] + bhr;
            float hz = acc1[i] + bhz;
            float hn = acc2[i] + bhn;
            float r = 1.f / (1.f + __expf(-(xr + hr)));
            float z = 1.f / (1.f + __expf(-(xz + hz)));
            float targ = xn + r * hn;
            targ = fminf(fmaxf(targ, -30.f), 30.f);
            float n = tanhf(targ);
            float hnew = (1.f - z) * n + z * hprev[i];
            hnew = fminf(fmaxf(hnew, -4.f), 4.f);   // invisible when correct
            hprev[i] = hnew;
            hout[b * H + cj] = f2bf(hnew);
            out[((size_t)b * TT + t) * H + cj] = hnew;
        }

        // ---- grid barrier (monotonic counter, absolute-t target) ----
        __syncthreads();                 // WG stores drained (vmcnt before barrier)
        if (threadIdx.x == 0) {
            // release: push this XCD's dirty L2 (h/out writes) to coherent point
            __hip_atomic_fetch_add(cnt, 1u, __ATOMIC_ACQ_REL, __HIP_MEMORY_SCOPE_AGENT);
            const unsigned int target = (unsigned int)(t + 1) * SCAN_BLOCKS;
            while (__hip_atomic_load(cnt, __ATOMIC_ACQUIRE, __HIP_MEMORY_SCOPE_AGENT) < target) {
                __builtin_amdgcn_s_sleep(2);
            }
        }
        __syncthreads();
        // every thread invalidates its CU's L1 / XCD's L2 so the remote h
        // writes are visible to the next step's loads (per-XCD L2 non-coherent)
        __threadfence();
    }

#pragma unroll
    for (int i = 0; i < 4; i++) hf[(m0 + quad * 4 + i) * H + cj] = hprev[i];
}

extern "C" void kernel_launch(void* const* d_in, const int* in_sizes, int n_in,
                              void* d_out, int out_size, void* d_ws, size_t ws_size,
                              hipStream_t stream) {
    const int*   tokens = (const int*)d_in[0];
    const float* h0     = (const float*)d_in[1];
    const float* emb    = (const float*)d_in[2];
    const float* W_ih   = (const float*)d_in[3];
    const float* W_hh   = (const float*)d_in[4];
    const float* b_ih   = (const float*)d_in[5];
    const float* b_hh   = (const float*)d_in[6];
    float*       out    = (float*)d_out;

    // ws: [0,1MiB) h state + barrier | [1MiB,+6MiB) W_ih bf16 | +6MiB W_hh bf16 | xp chunk
    char* ws = (char*)d_ws;
    float* hf0 = (float*)ws;                                // 256 KiB (f32 h)
    unsigned short* hb0 = (unsigned short*)(ws + 524288);   // 128 KiB
    unsigned short* hb1 = hb0 + BB * H;                     // 128 KiB
    unsigned int* cnt = (unsigned int*)(ws + 786432);       // barrier counter
    unsigned short* Wib = (unsigned short*)(ws + 1048576);          // 6 MiB
    unsigned short* Whb = (unsigned short*)(ws + 1048576 + 6291456);// 6 MiB
    unsigned short* xp  = (unsigned short*)(ws + 13631488);

    const size_t slab = (size_t)BB * G3 * 2;                // 393,216 B per t
    long avail = (long)ws_size - 13631488L;
    if (avail < 0) avail = 0;
    long tc = (avail / (long)slab) & ~1L;                   // even
    if (tc < 2) tc = 2;
    if (tc > TT) tc = TT;
    const int Tc = (int)tc;

    hipLaunchKernelGGL(cvt_f32_bf16, dim3(G3 * H / 1024), dim3(256), 0, stream, W_ih, Wib);
    hipLaunchKernelGGL(cvt_f32_bf16, dim3(G3 * H / 1024), dim3(256), 0, stream, W_hh, Whb);
    hipLaunchKernelGGL(init_all, dim3((BB * H) / 256), dim3(256), 0, stream, h0, hf0, hb0, cnt);

    for (int c0 = 0; c0 < TT; c0 += Tc) {
        const int Tl = (TT - c0 < Tc) ? (TT - c0) : Tc;     // even
        hipLaunchKernelGGL(gemm_xp, dim3(G3 / 128, Tl * BB / 128), dim3(256), 0, stream,
                           emb, tokens, Wib, b_ih, xp, c0 * BB);
        hipLaunchKernelGGL(gru_scan, dim3(SCAN_BLOCKS), dim3(256), 0, stream,
                           hb0, hb1, hf0, Whb, b_hh, xp, out, cnt, c0, Tl);
    }
}